// Round 5
// baseline (646.104 us; speedup 1.0000x reference)
//
#include <hip/hip_runtime.h>
#include <hip/hip_bf16.h>
#include <math.h>

#define NN 50000
#define NE 800000
#define FD 100
#define HD 128
#define CD 40
#define EPSF 1e-5f
#define NTILE 6250   // NE / 128 exactly
#define TPB_G1 5
#define GRID_G1 1250 // NTILE / TPB_G1

typedef __attribute__((ext_vector_type(8))) short short8;
typedef __attribute__((ext_vector_type(4))) float f32x4;

__device__ __forceinline__ unsigned short f2bf(float x) {
  union { __hip_bfloat16 h; unsigned short u; } cv;
  cv.h = __float2bfloat16(x);
  return cv.u;
}
__device__ __forceinline__ float bf2f(unsigned short b) {
  return __uint_as_float(((unsigned)b) << 16);
}

// row_ptr[i] = first edge index with seg_ids >= i
__global__ void k_rowptr(const int* __restrict__ seg, int* __restrict__ rp) {
  int i = blockIdx.x * blockDim.x + threadIdx.x;
  if (i > NN) return;
  int lo = 0, hi = NE;
  while (lo < hi) { int mid = (lo + hi) >> 1; if (seg[mid] < i) lo = mid + 1; else hi = mid; }
  rp[i] = lo;
}

// convert 32 f32 (in 8 float4) -> 4 swizzled short8 LDS writes (row stride 256B)
__device__ __forceinline__ void cvt_write256(const float4* gv, char* rowbase, int q, int sr) {
  const float* vf = (const float*)gv;
#pragma unroll
  for (int h = 0; h < 4; ++h) {
    short8 s;
#pragma unroll
    for (int e = 0; e < 8; ++e) s[e] = (short)f2bf(vf[h * 8 + e]);
    *(short8*)(rowbase + ((q * 64 + h * 16) ^ ((sr & 7) << 4))) = s;
  }
}

// ---------------- edge GEMM: nbr1 = bf16(nbr @ W1x^T), es/eq row stats ----------------
__global__ __launch_bounds__(512, 2) void k_gemm1(
    const float* __restrict__ nbr, const float* __restrict__ W1x,
    unsigned short* __restrict__ nbr1,
    float* __restrict__ es, float* __restrict__ eq) {
  __shared__ char lds[65536];  // two 32KB A buffers; buf0 doubles as B staging at start
  const int tid = threadIdx.x;
  const int sr = tid >> 2, q = tid & 3;
  const int w = tid >> 6, l = tid & 63, lr = l & 15, lh = l >> 4;

  // stage B = W1x (128 x 100 f32) -> bf16 swizzled into buf0
  {
    float4 gv[8];
    const float* src = W1x + (size_t)sr * FD;
#pragma unroll
    for (int i4 = 0; i4 < 8; ++i4) {
      const int c = q * 32 + i4 * 4;
      gv[i4] = (c < FD) ? *(const float4*)(src + c) : make_float4(0.f, 0.f, 0.f, 0.f);
    }
    cvt_write256(gv, lds + sr * 256, q, sr);
  }
  __syncthreads();
  // B fragments -> registers (reused for all tiles)
  short8 bfr[8][4];
#pragma unroll
  for (int nt = 0; nt < 8; ++nt) {
#pragma unroll
    for (int kk = 0; kk < 4; ++kk) {
      const int n = nt * 16 + lr;
      bfr[nt][kk] = *(short8*)(lds + n * 256 + ((lh * 16 + kk * 64) ^ ((n & 7) << 4)));
    }
  }
  __syncthreads();

  const int t0 = blockIdx.x * TPB_G1;
  float4 gv[8];
  // prologue: stage tile t0 into buf0
  {
    const float* src = nbr + (size_t)(t0 * 128 + sr) * FD;
#pragma unroll
    for (int i4 = 0; i4 < 8; ++i4) {
      const int c = q * 32 + i4 * 4;
      gv[i4] = (c < FD) ? *(const float4*)(src + c) : make_float4(0.f, 0.f, 0.f, 0.f);
    }
    cvt_write256(gv, lds + sr * 256, q, sr);
  }
  int cur = 0;
  for (int s = 0; s < TPB_G1; ++s) {
    // issue next tile's global loads early (latency hides under MFMA)
    if (s + 1 < TPB_G1) {
      const float* src = nbr + (size_t)((t0 + s + 1) * 128 + sr) * FD;
#pragma unroll
      for (int i4 = 0; i4 < 8; ++i4) {
        const int c = q * 32 + i4 * 4;
        gv[i4] = (c < FD) ? *(const float4*)(src + c) : make_float4(0.f, 0.f, 0.f, 0.f);
      }
    }
    __syncthreads();  // buf[cur] ready
    char* bufc = lds + cur * 32768;
    short8 af[4];
    const int arow = w * 16 + lr;
#pragma unroll
    for (int kk = 0; kk < 4; ++kk)
      af[kk] = *(short8*)(bufc + arow * 256 + ((lh * 16 + kk * 64) ^ ((arow & 7) << 4)));

    const size_t rowb = (size_t)(t0 + s) * 128;
    float rs[4] = {0.f, 0.f, 0.f, 0.f}, rq[4] = {0.f, 0.f, 0.f, 0.f};
#pragma unroll
    for (int nt = 0; nt < 8; ++nt) {
      f32x4 acc = {0.f, 0.f, 0.f, 0.f};
#pragma unroll
      for (int kk = 0; kk < 4; ++kk)
        acc = __builtin_amdgcn_mfma_f32_16x16x32_bf16(af[kk], bfr[nt][kk], acc, 0, 0, 0);
      const int col = nt * 16 + lr;
#pragma unroll
      for (int r = 0; r < 4; ++r) {
        const float val = acc[r];
        nbr1[(rowb + w * 16 + lh * 4 + r) * HD + col] = f2bf(val);
        rs[r] += val;
        rq[r] = fmaf(val, val, rq[r]);
      }
    }
#pragma unroll
    for (int r = 0; r < 4; ++r) {
      float a = rs[r], b = rq[r];
#pragma unroll
      for (int off = 1; off < 16; off <<= 1) { a += __shfl_xor(a, off); b += __shfl_xor(b, off); }
      if (lr == 0) {
        const size_t rg = rowb + w * 16 + lh * 4 + r;
        es[rg] = a; eq[rg] = b;
      }
    }
    if (s + 1 < TPB_G1) cvt_write256(gv, lds + (cur ^ 1) * 32768 + sr * 256, q, sr);
    cur ^= 1;
  }
}

// ---------------- segment sums, coalesced chunk + boundary atomics ----------------
__global__ __launch_bounds__(256) void k_f(
    const float* __restrict__ nbr, const int* __restrict__ seg, float* __restrict__ fsum) {
  __shared__ float L[128][104];
  __shared__ int segL[128];
  const int tid = threadIdx.x;
  const size_t base = (size_t)blockIdx.x * 128;
  for (int idx = tid; idx < 3200; idx += 256) {
    const int row = idx / 25, c4 = idx - row * 25;
    float4 v = *(const float4*)(nbr + (base + row) * FD + c4 * 4);
    *(float4*)&L[row][c4 * 4] = v;
  }
  if (tid < 128) segL[tid] = seg[base + tid];
  __syncthreads();
  if (tid < FD) {
    const int nd0 = segL[0], ndL = segL[127];
    int curn = nd0; float acc = 0.f;
    for (int row = 0; row < 128; ++row) {
      const int nd = segL[row];
      if (nd != curn) {
        if (curn == nd0 || curn == ndL) atomicAdd(&fsum[(size_t)curn * FD + tid], acc);
        else fsum[(size_t)curn * FD + tid] = acc;
        acc = 0.f; curn = nd;
      }
      acc += L[row][tid];
    }
    atomicAdd(&fsum[(size_t)curn * FD + tid], acc);
  }
}

__global__ void k_nodestats(const int* __restrict__ rp, const float* __restrict__ es,
                            const float* __restrict__ eq, float2* __restrict__ smi,
                            float* __restrict__ rcv) {
  const int i = blockIdx.x * blockDim.x + threadIdx.x;
  if (i >= NN) return;
  const int s = rp[i], e = rp[i + 1];
  float S = 0.f, Q = 0.f;
  for (int ed = s; ed < e; ++ed) { S += es[ed]; Q += eq[ed]; }
  const int cnt = e - s;
  const float ne = fmaxf((float)cnt * (float)HD, 1.f);
  const float sm = S / ne;
  const float var = Q / ne - sm * sm;
  smi[i] = make_float2(sm, rsqrtf(var + EPSF));
  rcv[i] = 1.f / (float)(cnt > 0 ? cnt : 1);
}

__global__ __launch_bounds__(256) void k_f2(
    const unsigned short* __restrict__ nbr1, const int* __restrict__ seg,
    const float2* __restrict__ smi, const float* __restrict__ g1p,
    const float* __restrict__ b1p, float* __restrict__ f2sum) {
  __shared__ float L[128][132];
  __shared__ int segL[128];
  __shared__ float2 smrow[128];
  const int tid = threadIdx.x;
  const size_t base = (size_t)blockIdx.x * 128;
  for (int idx = tid; idx < 2048; idx += 256) {
    const int row = idx >> 4, c8 = idx & 15;
    short8 v = *(const short8*)(nbr1 + (base + row) * HD + c8 * 8);
    float4 a, b;
    a.x = bf2f((unsigned short)v[0]); a.y = bf2f((unsigned short)v[1]);
    a.z = bf2f((unsigned short)v[2]); a.w = bf2f((unsigned short)v[3]);
    b.x = bf2f((unsigned short)v[4]); b.y = bf2f((unsigned short)v[5]);
    b.z = bf2f((unsigned short)v[6]); b.w = bf2f((unsigned short)v[7]);
    *(float4*)&L[row][c8 * 8] = a;
    *(float4*)&L[row][c8 * 8 + 4] = b;
  }
  if (tid < 128) {
    const int nd = seg[base + tid];
    segL[tid] = nd;
    smrow[tid] = smi[nd];
  }
  __syncthreads();
  const float g = g1p[0], bb = b1p[0];
  if (tid < HD) {
    const int nd0 = segL[0], ndL = segL[127];
    int curn = nd0; float acc = 0.f;
    for (int row = 0; row < 128; ++row) {
      const int nd = segL[row];
      if (nd != curn) {
        if (curn == nd0 || curn == ndL) atomicAdd(&f2sum[(size_t)curn * HD + tid], acc);
        else f2sum[(size_t)curn * HD + tid] = acc;
        acc = 0.f; curn = nd;
      }
      const float2 mi = smrow[row];
      acc += fmaxf(fmaf(g, (L[row][tid] - mi.x) * mi.y, bb), 0.f);
    }
    atomicAdd(&f2sum[(size_t)curn * HD + tid], acc);
  }
}

// ---------------- node GEMMs (MFMA, K=256 two-half) ----------------
// L2=false: out = x@W1x^T + (fsum*rcv)@W1n^T, stats -> so[0..1]
// L2=true : out = bnrelu(hpre)@W2x^T + (f2sum*rcv)@W2n^T, stats -> so[0..1]
template <bool L2>
__global__ __launch_bounds__(512) void k_ngemm(
    const float* __restrict__ P1, const float* __restrict__ P2,
    const float* __restrict__ rcv,
    const float* __restrict__ WA, const float* __restrict__ WB,
    const float* __restrict__ stats_in,
    const float* __restrict__ gp, const float* __restrict__ bp,
    float* __restrict__ out, float* __restrict__ so) {
  constexpr int KH = L2 ? HD : FD;  // valid source cols per half
  __shared__ char lds[131072];      // A @0 (64KB), B @65536 (64KB); rows 512B
  __shared__ float sred[16];
  const int tid = threadIdx.x;
  float a1 = 1.f, c1 = 0.f;
  if (L2) {
    const float m = stats_in[0] * (1.f / ((float)NN * (float)HD));
    const float var = stats_in[1] * (1.f / ((float)NN * (float)HD)) - m * m;
    const float inv = rsqrtf(var + EPSF);
    const float g = gp[0], bb = bp[0];
    a1 = g * inv; c1 = bb - g * m * inv;
  }
  const int sr = tid >> 2, q = tid & 3;
  const size_t rg = (size_t)blockIdx.x * 128 + sr;
  // ---- stage A ----
  {
    const bool half2 = (q >= 2);
    const int cbase = (q & 1) * 64;
    const float* src = (half2 ? P2 : P1) + rg * KH;
    const float sc = half2 ? ((rg < NN) ? rcv[rg] : 0.f) : 1.f;
    float v[64];
#pragma unroll
    for (int i4 = 0; i4 < 16; ++i4) {
      const int c = cbase + i4 * 4;
      float4 t = make_float4(0.f, 0.f, 0.f, 0.f);
      if (rg < NN && c < KH) t = *(const float4*)(src + c);
      float e0 = t.x, e1 = t.y, e2 = t.z, e3 = t.w;
      if (half2) { e0 *= sc; e1 *= sc; e2 *= sc; e3 *= sc; }
      else if (L2) {
        e0 = fmaxf(fmaf(a1, e0, c1), 0.f); e1 = fmaxf(fmaf(a1, e1, c1), 0.f);
        e2 = fmaxf(fmaf(a1, e2, c1), 0.f); e3 = fmaxf(fmaf(a1, e3, c1), 0.f);
      }
      v[i4 * 4 + 0] = e0; v[i4 * 4 + 1] = e1; v[i4 * 4 + 2] = e2; v[i4 * 4 + 3] = e3;
    }
    char* db = lds + sr * 512;
#pragma unroll
    for (int h = 0; h < 8; ++h) {
      short8 s8;
#pragma unroll
      for (int e = 0; e < 8; ++e) s8[e] = (short)f2bf(v[h * 8 + e]);
      *(short8*)(db + ((q * 128 + h * 16) ^ ((sr & 7) << 4))) = s8;
    }
  }
  // ---- stage B ----
  {
    const bool half2 = (q >= 2);
    const int cbase = (q & 1) * 64;
    const float* src = (half2 ? WB : WA) + (size_t)sr * KH;
    float v[64];
#pragma unroll
    for (int i4 = 0; i4 < 16; ++i4) {
      const int c = cbase + i4 * 4;
      float4 t = make_float4(0.f, 0.f, 0.f, 0.f);
      if (c < KH) t = *(const float4*)(src + c);
      v[i4 * 4 + 0] = t.x; v[i4 * 4 + 1] = t.y; v[i4 * 4 + 2] = t.z; v[i4 * 4 + 3] = t.w;
    }
    char* db = lds + 65536 + sr * 512;
#pragma unroll
    for (int h = 0; h < 8; ++h) {
      short8 s8;
#pragma unroll
      for (int e = 0; e < 8; ++e) s8[e] = (short)f2bf(v[h * 8 + e]);
      *(short8*)(db + ((q * 128 + h * 16) ^ ((sr & 7) << 4))) = s8;
    }
  }
  __syncthreads();
  // ---- compute ----
  const int w = tid >> 6, l = tid & 63, lr = l & 15, lh = l >> 4;
  short8 af[8];
  const int arow = w * 16 + lr;
#pragma unroll
  for (int kk = 0; kk < 8; ++kk)
    af[kk] = *(short8*)(lds + arow * 512 + ((lh * 16 + kk * 64) ^ ((arow & 7) << 4)));
  float ls = 0.f, lsq = 0.f;
  const char* B = lds + 65536;
#pragma unroll
  for (int nt = 0; nt < 8; ++nt) {
    f32x4 acc = {0.f, 0.f, 0.f, 0.f};
#pragma unroll
    for (int kk = 0; kk < 8; ++kk) {
      const int n = nt * 16 + lr;
      short8 bfg = *(const short8*)(B + n * 512 + ((lh * 16 + kk * 64) ^ ((n & 7) << 4)));
      acc = __builtin_amdgcn_mfma_f32_16x16x32_bf16(af[kk], bfg, acc, 0, 0, 0);
    }
    const int col = nt * 16 + lr;
#pragma unroll
    for (int r = 0; r < 4; ++r) {
      const float val = acc[r];
      const size_t rg2 = (size_t)blockIdx.x * 128 + w * 16 + lh * 4 + r;
      if (rg2 < NN) out[rg2 * HD + col] = val;
      ls += val;
      lsq = fmaf(val, val, lsq);
    }
  }
#pragma unroll
  for (int off = 32; off > 0; off >>= 1) { ls += __shfl_down(ls, off); lsq += __shfl_down(lsq, off); }
  if ((tid & 63) == 0) { sred[(tid >> 6) * 2] = ls; sred[(tid >> 6) * 2 + 1] = lsq; }
  __syncthreads();
  if (tid == 0) {
    float S = 0.f, Q = 0.f;
#pragma unroll
    for (int i = 0; i < 8; ++i) { S += sred[i * 2]; Q += sred[i * 2 + 1]; }
    atomicAdd(&so[0], S);
    atomicAdd(&so[1], Q);
  }
}

// ---------------- classifier: out = bnrelu(h2) @ Wc^T + bc ----------------
__global__ __launch_bounds__(512) void k_cls(
    const float* __restrict__ h2, const float* __restrict__ Wc,
    const float* __restrict__ bc, const float* __restrict__ stats,
    const float* __restrict__ gp, const float* __restrict__ bp,
    float* __restrict__ out) {
  __shared__ char lds[45056];  // A @0 (32KB, 256B rows), B @32768 (48 x 256B)
  const int tid = threadIdx.x;
  const float m = stats[0] * (1.f / ((float)NN * (float)HD));
  const float var = stats[1] * (1.f / ((float)NN * (float)HD)) - m * m;
  const float inv = rsqrtf(var + EPSF);
  const float g = gp[0], bb = bp[0];
  const float a2 = g * inv, c2 = bb - g * m * inv;
  const int sr = tid >> 2, q = tid & 3;
  const size_t rg = (size_t)blockIdx.x * 128 + sr;
  {
    float4 gv[8];
#pragma unroll
    for (int i4 = 0; i4 < 8; ++i4) {
      const int c = q * 32 + i4 * 4;
      float4 t = (rg < NN) ? *(const float4*)(h2 + rg * HD + c) : make_float4(0.f, 0.f, 0.f, 0.f);
      t.x = fmaxf(fmaf(a2, t.x, c2), 0.f); t.y = fmaxf(fmaf(a2, t.y, c2), 0.f);
      t.z = fmaxf(fmaf(a2, t.z, c2), 0.f); t.w = fmaxf(fmaf(a2, t.w, c2), 0.f);
      gv[i4] = t;
    }
    cvt_write256(gv, lds + sr * 256, q, sr);
  }
  if (tid < 192) {
    const int bn = tid >> 2, bq = tid & 3;
    float4 gv[8];
#pragma unroll
    for (int i4 = 0; i4 < 8; ++i4) {
      const int c = bq * 32 + i4 * 4;
      gv[i4] = (bn < CD) ? *(const float4*)(Wc + (size_t)bn * HD + c) : make_float4(0.f, 0.f, 0.f, 0.f);
    }
    cvt_write256(gv, lds + 32768 + bn * 256, bq, bn);
  }
  __syncthreads();
  const int w = tid >> 6, l = tid & 63, lr = l & 15, lh = l >> 4;
  short8 af[4];
  const int arow = w * 16 + lr;
#pragma unroll
  for (int kk = 0; kk < 4; ++kk)
    af[kk] = *(short8*)(lds + arow * 256 + ((lh * 16 + kk * 64) ^ ((arow & 7) << 4)));
#pragma unroll
  for (int nt = 0; nt < 3; ++nt) {
    f32x4 acc = {0.f, 0.f, 0.f, 0.f};
#pragma unroll
    for (int kk = 0; kk < 4; ++kk) {
      const int n = nt * 16 + lr;
      short8 bfg = *(const short8*)(lds + 32768 + n * 256 + ((lh * 16 + kk * 64) ^ ((n & 7) << 4)));
      acc = __builtin_amdgcn_mfma_f32_16x16x32_bf16(af[kk], bfg, acc, 0, 0, 0);
    }
    const int col = nt * 16 + lr;
    if (col < CD) {
      const float bias = bc[col];
#pragma unroll
      for (int r = 0; r < 4; ++r) {
        const size_t rg2 = (size_t)blockIdx.x * 128 + w * 16 + lh * 4 + r;
        if (rg2 < NN) out[rg2 * CD + col] = acc[r] + bias;
      }
    }
  }
}

extern "C" void kernel_launch(void* const* d_in, const int* in_sizes, int n_in,
                              void* d_out, int out_size, void* d_ws, size_t ws_size,
                              hipStream_t stream) {
  const float* x   = (const float*)d_in[0];
  const float* nbr = (const float*)d_in[1];
  const int*   seg = (const int*)d_in[2];
  const float* W1x = (const float*)d_in[3];
  const float* W1n = (const float*)d_in[4];
  const float* g1  = (const float*)d_in[5];
  const float* b1  = (const float*)d_in[6];
  const float* W2x = (const float*)d_in[7];
  const float* W2n = (const float*)d_in[8];
  const float* g2  = (const float*)d_in[9];
  const float* b2  = (const float*)d_in[10];
  const float* Wc  = (const float*)d_in[11];
  const float* bc  = (const float*)d_in[12];
  float* out = (float*)d_out;

  char* p = (char*)d_ws;
  auto alloc = [&](size_t bytes) {
    char* q = p;
    p += (bytes + 255) & ~(size_t)255;
    return q;
  };
  int*    rp    = (int*)   alloc(sizeof(int) * (NN + 1));
  float*  fsum  = (float*) alloc(sizeof(float) * (size_t)NN * FD);
  float*  f2sum = (float*) alloc(sizeof(float) * (size_t)NN * HD);
  float*  hpre  = (float*) alloc(sizeof(float) * (size_t)NN * HD);
  float*  h2    = (float*) alloc(sizeof(float) * (size_t)NN * HD);
  float*  stats = (float*) alloc(sizeof(float) * 4);
  unsigned short* nbr1 = (unsigned short*)alloc(sizeof(unsigned short) * (size_t)NE * HD);
  float*  es    = (float*) alloc(sizeof(float) * (size_t)NE);
  float*  eq    = (float*) alloc(sizeof(float) * (size_t)NE);
  float2* smi   = (float2*)alloc(sizeof(float2) * (size_t)NN);
  float*  rcv   = (float*) alloc(sizeof(float) * (size_t)NN);

  hipMemsetAsync(stats, 0, sizeof(float) * 4, stream);
  hipMemsetAsync(fsum, 0, sizeof(float) * (size_t)NN * FD, stream);
  hipMemsetAsync(f2sum, 0, sizeof(float) * (size_t)NN * HD, stream);

  k_rowptr<<<(NN + 256) / 256, 256, 0, stream>>>(seg, rp);
  k_gemm1<<<GRID_G1, 512, 0, stream>>>(nbr, W1x, nbr1, es, eq);
  k_f<<<NTILE, 256, 0, stream>>>(nbr, seg, fsum);
  k_nodestats<<<(NN + 255) / 256, 256, 0, stream>>>(rp, es, eq, smi, rcv);
  k_f2<<<NTILE, 256, 0, stream>>>(nbr1, seg, smi, g1, b1, f2sum);
  k_ngemm<false><<<391, 512, 0, stream>>>(x, fsum, rcv, W1x, W1n, stats, g1, b1, hpre, stats);
  k_ngemm<true><<<391, 512, 0, stream>>>(hpre, f2sum, rcv, W2x, W2n, stats, g1, b1, h2, stats + 2);
  k_cls<<<391, 512, 0, stream>>>(h2, Wc, bc, stats + 2, g2, b2, out);
}

// Round 6
// 549.638 us; speedup vs baseline: 1.1755x; 1.1755x over previous
//
#include <hip/hip_runtime.h>
#include <hip/hip_bf16.h>
#include <math.h>

#define NN 50000
#define NE 800000
#define FD 100
#define HD 128
#define CD 40
#define EPSF 1e-5f
#define NTILE 6250   // NE / 128 exactly
#define TPB_G1 5
#define GRID_G1 1250 // NTILE / TPB_G1

typedef __attribute__((ext_vector_type(8))) short short8;
typedef __attribute__((ext_vector_type(4))) float f32x4;

__device__ __forceinline__ unsigned short f2bf(float x) {
  union { __hip_bfloat16 h; unsigned short u; } cv;
  cv.h = __float2bfloat16(x);
  return cv.u;
}
__device__ __forceinline__ float bf2f(unsigned short b) {
  return __uint_as_float(((unsigned)b) << 16);
}

// row_ptr[i] = first edge index with seg_ids >= i
__global__ void k_rowptr(const int* __restrict__ seg, int* __restrict__ rp) {
  int i = blockIdx.x * blockDim.x + threadIdx.x;
  if (i > NN) return;
  int lo = 0, hi = NE;
  while (lo < hi) { int mid = (lo + hi) >> 1; if (seg[mid] < i) lo = mid + 1; else hi = mid; }
  rp[i] = lo;
}

// convert 32 f32 (in 8 float4) -> 4 swizzled short8 LDS writes (row stride 256B)
__device__ __forceinline__ void cvt_write256(const float4* gv, char* rowbase, int q, int sr) {
  const float* vf = (const float*)gv;
#pragma unroll
  for (int h = 0; h < 4; ++h) {
    short8 s;
#pragma unroll
    for (int e = 0; e < 8; ++e) s[e] = (short)f2bf(vf[h * 8 + e]);
    *(short8*)(rowbase + ((q * 64 + h * 16) ^ ((sr & 7) << 4))) = s;
  }
}

// ---------------- pass 1: MFMA edge GEMM -> es/eq row stats + fsum (segment sums of nbr) ----
// 128x128 tile, B=W1x in VGPRs, A double-buffered, fused quarter-scan of the staged
// bf16 A-tile for fsum (interior runs -> store, boundary runs -> atomicAdd).
__global__ __launch_bounds__(512, 2) void k_gemm1(
    const float* __restrict__ nbr, const int* __restrict__ seg,
    const float* __restrict__ W1x,
    float* __restrict__ es, float* __restrict__ eq, float* __restrict__ fsum) {
  __shared__ char lds[65536];     // two 32KB A buffers; buf0 doubles as B staging
  __shared__ int segL[2][128];
  const int tid = threadIdx.x;
  const int sr = tid >> 2, q = tid & 3;
  const int w = tid >> 6, l = tid & 63, lr = l & 15, lh = l >> 4;

  // stage B = W1x (128 x 100 f32) -> bf16 swizzled into buf0
  {
    float4 gv[8];
    const float* src = W1x + (size_t)sr * FD;
#pragma unroll
    for (int i4 = 0; i4 < 8; ++i4) {
      const int c = q * 32 + i4 * 4;
      gv[i4] = (c < FD) ? *(const float4*)(src + c) : make_float4(0.f, 0.f, 0.f, 0.f);
    }
    cvt_write256(gv, lds + sr * 256, q, sr);
  }
  __syncthreads();
  short8 bfr[8][4];
#pragma unroll
  for (int nt = 0; nt < 8; ++nt) {
#pragma unroll
    for (int kk = 0; kk < 4; ++kk) {
      const int n = nt * 16 + lr;
      bfr[nt][kk] = *(short8*)(lds + n * 256 + ((lh * 16 + kk * 64) ^ ((n & 7) << 4)));
    }
  }
  __syncthreads();

  const int t0 = blockIdx.x * TPB_G1;
  // prologue: stage tile t0 + its seg ids
  {
    float4 gv[8];
    const float* src = nbr + (size_t)(t0 * 128 + sr) * FD;
#pragma unroll
    for (int i4 = 0; i4 < 8; ++i4) {
      const int c = q * 32 + i4 * 4;
      gv[i4] = (c < FD) ? *(const float4*)(src + c) : make_float4(0.f, 0.f, 0.f, 0.f);
    }
    cvt_write256(gv, lds + sr * 256, q, sr);
    if (tid < 128) segL[0][tid] = seg[t0 * 128 + tid];
  }
  int cur = 0;
  for (int s = 0; s < TPB_G1; ++s) {
    float4 gv[8];
    int sgn = 0;
    if (s + 1 < TPB_G1) {
      const float* src = nbr + (size_t)((t0 + s + 1) * 128 + sr) * FD;
#pragma unroll
      for (int i4 = 0; i4 < 8; ++i4) {
        const int c = q * 32 + i4 * 4;
        gv[i4] = (c < FD) ? *(const float4*)(src + c) : make_float4(0.f, 0.f, 0.f, 0.f);
      }
      if (tid < 128) sgn = seg[(t0 + s + 1) * 128 + tid];
    }
    __syncthreads();  // buf[cur] + segL[cur] ready; prev scan complete
    const char* bufc = lds + cur * 32768;
    short8 af[4];
    const int arow = w * 16 + lr;
#pragma unroll
    for (int kk = 0; kk < 4; ++kk)
      af[kk] = *(short8*)(bufc + arow * 256 + ((lh * 16 + kk * 64) ^ ((arow & 7) << 4)));

    const size_t rowb = (size_t)(t0 + s) * 128;
    float rs[4] = {0.f, 0.f, 0.f, 0.f}, rq[4] = {0.f, 0.f, 0.f, 0.f};
#pragma unroll
    for (int nt = 0; nt < 8; ++nt) {
      f32x4 acc = {0.f, 0.f, 0.f, 0.f};
#pragma unroll
      for (int kk = 0; kk < 4; ++kk)
        acc = __builtin_amdgcn_mfma_f32_16x16x32_bf16(af[kk], bfr[nt][kk], acc, 0, 0, 0);
#pragma unroll
      for (int r = 0; r < 4; ++r) {
        const float val = acc[r];
        rs[r] += val;
        rq[r] = fmaf(val, val, rq[r]);
      }
    }
#pragma unroll
    for (int r = 0; r < 4; ++r) {
      float a = rs[r], b = rq[r];
#pragma unroll
      for (int off = 1; off < 16; off <<= 1) { a += __shfl_xor(a, off); b += __shfl_xor(b, off); }
      if (lr == 0) {
        const size_t rg = rowb + w * 16 + lh * 4 + r;
        es[rg] = a; eq[rg] = b;
      }
    }
    // stage next tile into buf[cur^1]
    if (s + 1 < TPB_G1) {
      cvt_write256(gv, lds + (cur ^ 1) * 32768 + sr * 256, q, sr);
      if (tid < 128) segL[cur ^ 1][tid] = sgn;
    }
    // fused fsum scan of A-tile (bf16 nbr values), quarter-split segmented sum
    {
      const int qq = tid >> 7, j = tid & 127;
      if (j < FD) {
        const int r0 = qq * 32;
        const int* sl = segL[cur];
        int curn = sl[r0];
        float acc = 0.f;
        bool inside = false;
        for (int rr = 0; rr < 32; ++rr) {
          const int row = r0 + rr;
          const int nd = sl[row];
          if (nd != curn) {
            float* dst = fsum + (size_t)curn * FD + j;
            if (inside) *dst = acc; else atomicAdd(dst, acc);
            inside = true; acc = 0.f; curn = nd;
          }
          acc += bf2f(*(const unsigned short*)(bufc + row * 256 + ((j * 2) ^ ((row & 7) << 4))));
        }
        atomicAdd(fsum + (size_t)curn * FD + j, acc);
      }
    }
    cur ^= 1;
  }
}

// per-node BN stats from per-edge sums: sm, inv, rc
__global__ void k_nodestats(const int* __restrict__ rp, const float* __restrict__ es,
                            const float* __restrict__ eq, float2* __restrict__ smi,
                            float* __restrict__ rcv) {
  const int i = blockIdx.x * blockDim.x + threadIdx.x;
  if (i >= NN) return;
  const int s = rp[i], e = rp[i + 1];
  float S = 0.f, Q = 0.f;
  for (int ed = s; ed < e; ++ed) { S += es[ed]; Q += eq[ed]; }
  const int cnt = e - s;
  const float ne = fmaxf((float)cnt * (float)HD, 1.f);
  const float sm = S / ne;
  const float var = Q / ne - sm * sm;
  smi[i] = make_float2(sm, rsqrtf(var + EPSF));
  rcv[i] = 1.f / (float)(cnt > 0 ? cnt : 1);
}

// ---------------- pass 2: recompute MFMA, BN+ReLU in-register, scan -> f2sum ----------------
__global__ __launch_bounds__(512, 2) void k_fuse2(
    const float* __restrict__ nbr, const int* __restrict__ seg,
    const float* __restrict__ W1x, const float2* __restrict__ smi,
    const float* __restrict__ g1p, const float* __restrict__ b1p,
    float* __restrict__ f2sum) {
  __shared__ char A[32768];       // single A buffer (reg-prefetch covers latency)
  __shared__ char P[32768];       // relu'd tile, bf16 swizzled
  __shared__ int segL[2][128];
  __shared__ float2 smrow[2][128];
  const int tid = threadIdx.x;
  const int sr = tid >> 2, q = tid & 3;
  const int w = tid >> 6, l = tid & 63, lr = l & 15, lh = l >> 4;
  const float g1 = g1p[0], b1 = b1p[0];

  // stage B = W1x transiently in A
  {
    float4 gv[8];
    const float* src = W1x + (size_t)sr * FD;
#pragma unroll
    for (int i4 = 0; i4 < 8; ++i4) {
      const int c = q * 32 + i4 * 4;
      gv[i4] = (c < FD) ? *(const float4*)(src + c) : make_float4(0.f, 0.f, 0.f, 0.f);
    }
    cvt_write256(gv, A + sr * 256, q, sr);
  }
  __syncthreads();
  short8 bfr[8][4];
#pragma unroll
  for (int nt = 0; nt < 8; ++nt) {
#pragma unroll
    for (int kk = 0; kk < 4; ++kk) {
      const int n = nt * 16 + lr;
      bfr[nt][kk] = *(short8*)(A + n * 256 + ((lh * 16 + kk * 64) ^ ((n & 7) << 4)));
    }
  }
  __syncthreads();

  const int t0 = blockIdx.x * TPB_G1;
  // prologue: stage tile t0 + seg/smi rows
  {
    float4 gv[8];
    const float* src = nbr + (size_t)(t0 * 128 + sr) * FD;
#pragma unroll
    for (int i4 = 0; i4 < 8; ++i4) {
      const int c = q * 32 + i4 * 4;
      gv[i4] = (c < FD) ? *(const float4*)(src + c) : make_float4(0.f, 0.f, 0.f, 0.f);
    }
    cvt_write256(gv, A + sr * 256, q, sr);
    if (tid < 128) {
      const int nd = seg[t0 * 128 + tid];
      segL[0][tid] = nd;
      smrow[0][tid] = smi[nd];
    }
  }
  int cur = 0;
  for (int s = 0; s < TPB_G1; ++s) {
    float4 gv[8];
    int sgn = 0;
    float2 smn = make_float2(0.f, 0.f);
    if (s + 1 < TPB_G1) {
      const float* src = nbr + (size_t)((t0 + s + 1) * 128 + sr) * FD;
#pragma unroll
      for (int i4 = 0; i4 < 8; ++i4) {
        const int c = q * 32 + i4 * 4;
        gv[i4] = (c < FD) ? *(const float4*)(src + c) : make_float4(0.f, 0.f, 0.f, 0.f);
      }
      if (tid < 128) { sgn = seg[(t0 + s + 1) * 128 + tid]; smn = smi[sgn]; }
    }
    __syncthreads();  // A/segL/smrow[cur] ready; P free (prev scan done)
    short8 af[4];
    const int arow = w * 16 + lr;
#pragma unroll
    for (int kk = 0; kk < 4; ++kk)
      af[kk] = *(short8*)(A + arow * 256 + ((lh * 16 + kk * 64) ^ ((arow & 7) << 4)));
    float2 mi[4];
#pragma unroll
    for (int r = 0; r < 4; ++r) mi[r] = smrow[cur][w * 16 + lh * 4 + r];
#pragma unroll
    for (int nt = 0; nt < 8; ++nt) {
      f32x4 acc = {0.f, 0.f, 0.f, 0.f};
#pragma unroll
      for (int kk = 0; kk < 4; ++kk)
        acc = __builtin_amdgcn_mfma_f32_16x16x32_bf16(af[kk], bfr[nt][kk], acc, 0, 0, 0);
      const int col = nt * 16 + lr;
#pragma unroll
      for (int r = 0; r < 4; ++r) {
        const int row = w * 16 + lh * 4 + r;
        const float v = fmaxf(fmaf(g1, (acc[r] - mi[r].x) * mi[r].y, b1), 0.f);
        *(unsigned short*)(P + row * 256 + ((col * 2) ^ ((row & 7) << 4))) = f2bf(v);
      }
    }
    __syncthreads();  // P complete; all af reads done
    // stage next tile into A (disjoint from P/segL[cur]); frees gv before scan
    if (s + 1 < TPB_G1) {
      cvt_write256(gv, A + sr * 256, q, sr);
      if (tid < 128) { segL[cur ^ 1][tid] = sgn; smrow[cur ^ 1][tid] = smn; }
    }
    // quarter-split segmented scan of P -> f2sum
    {
      const int qq = tid >> 7, j = tid & 127;
      const int r0 = qq * 32;
      const int* sl = segL[cur];
      int curn = sl[r0];
      float acc = 0.f;
      bool inside = false;
      for (int rr = 0; rr < 32; ++rr) {
        const int row = r0 + rr;
        const int nd = sl[row];
        if (nd != curn) {
          float* dst = f2sum + (size_t)curn * HD + j;
          if (inside) *dst = acc; else atomicAdd(dst, acc);
          inside = true; acc = 0.f; curn = nd;
        }
        acc += bf2f(*(const unsigned short*)(P + row * 256 + ((j * 2) ^ ((row & 7) << 4))));
      }
      atomicAdd(f2sum + (size_t)curn * HD + j, acc);
    }
    cur ^= 1;
  }
}

// ---------------- node GEMMs (MFMA, K=256 two-half) ----------------
template <bool L2>
__global__ __launch_bounds__(512) void k_ngemm(
    const float* __restrict__ P1, const float* __restrict__ P2,
    const float* __restrict__ rcv,
    const float* __restrict__ WA, const float* __restrict__ WB,
    const float* __restrict__ stats_in,
    const float* __restrict__ gp, const float* __restrict__ bp,
    float* __restrict__ out, float* __restrict__ so) {
  constexpr int KH = L2 ? HD : FD;
  __shared__ char lds[131072];
  __shared__ float sred[16];
  const int tid = threadIdx.x;
  float a1 = 1.f, c1 = 0.f;
  if (L2) {
    const float m = stats_in[0] * (1.f / ((float)NN * (float)HD));
    const float var = stats_in[1] * (1.f / ((float)NN * (float)HD)) - m * m;
    const float inv = rsqrtf(var + EPSF);
    const float g = gp[0], bb = bp[0];
    a1 = g * inv; c1 = bb - g * m * inv;
  }
  const int sr = tid >> 2, q = tid & 3;
  const size_t rg = (size_t)blockIdx.x * 128 + sr;
  {
    const bool half2 = (q >= 2);
    const int cbase = (q & 1) * 64;
    const float* src = (half2 ? P2 : P1) + rg * KH;
    const float sc = half2 ? ((rg < NN) ? rcv[rg] : 0.f) : 1.f;
    float v[64];
#pragma unroll
    for (int i4 = 0; i4 < 16; ++i4) {
      const int c = cbase + i4 * 4;
      float4 t = make_float4(0.f, 0.f, 0.f, 0.f);
      if (rg < NN && c < KH) t = *(const float4*)(src + c);
      float e0 = t.x, e1 = t.y, e2 = t.z, e3 = t.w;
      if (half2) { e0 *= sc; e1 *= sc; e2 *= sc; e3 *= sc; }
      else if (L2) {
        e0 = fmaxf(fmaf(a1, e0, c1), 0.f); e1 = fmaxf(fmaf(a1, e1, c1), 0.f);
        e2 = fmaxf(fmaf(a1, e2, c1), 0.f); e3 = fmaxf(fmaf(a1, e3, c1), 0.f);
      }
      v[i4 * 4 + 0] = e0; v[i4 * 4 + 1] = e1; v[i4 * 4 + 2] = e2; v[i4 * 4 + 3] = e3;
    }
    char* db = lds + sr * 512;
#pragma unroll
    for (int h = 0; h < 8; ++h) {
      short8 s8;
#pragma unroll
      for (int e = 0; e < 8; ++e) s8[e] = (short)f2bf(v[h * 8 + e]);
      *(short8*)(db + ((q * 128 + h * 16) ^ ((sr & 7) << 4))) = s8;
    }
  }
  {
    const bool half2 = (q >= 2);
    const int cbase = (q & 1) * 64;
    const float* src = (half2 ? WB : WA) + (size_t)sr * KH;
    float v[64];
#pragma unroll
    for (int i4 = 0; i4 < 16; ++i4) {
      const int c = cbase + i4 * 4;
      float4 t = make_float4(0.f, 0.f, 0.f, 0.f);
      if (c < KH) t = *(const float4*)(src + c);
      v[i4 * 4 + 0] = t.x; v[i4 * 4 + 1] = t.y; v[i4 * 4 + 2] = t.z; v[i4 * 4 + 3] = t.w;
    }
    char* db = lds + 65536 + sr * 512;
#pragma unroll
    for (int h = 0; h < 8; ++h) {
      short8 s8;
#pragma unroll
      for (int e = 0; e < 8; ++e) s8[e] = (short)f2bf(v[h * 8 + e]);
      *(short8*)(db + ((q * 128 + h * 16) ^ ((sr & 7) << 4))) = s8;
    }
  }
  __syncthreads();
  const int w = tid >> 6, l = tid & 63, lr = l & 15, lh = l >> 4;
  short8 af[8];
  const int arow = w * 16 + lr;
#pragma unroll
  for (int kk = 0; kk < 8; ++kk)
    af[kk] = *(short8*)(lds + arow * 512 + ((lh * 16 + kk * 64) ^ ((arow & 7) << 4)));
  float ls = 0.f, lsq = 0.f;
  const char* B = lds + 65536;
#pragma unroll
  for (int nt = 0; nt < 8; ++nt) {
    f32x4 acc = {0.f, 0.f, 0.f, 0.f};
#pragma unroll
    for (int kk = 0; kk < 8; ++kk) {
      const int n = nt * 16 + lr;
      short8 bfg = *(const short8*)(B + n * 512 + ((lh * 16 + kk * 64) ^ ((n & 7) << 4)));
      acc = __builtin_amdgcn_mfma_f32_16x16x32_bf16(af[kk], bfg, acc, 0, 0, 0);
    }
    const int col = nt * 16 + lr;
#pragma unroll
    for (int r = 0; r < 4; ++r) {
      const float val = acc[r];
      const size_t rg2 = (size_t)blockIdx.x * 128 + w * 16 + lh * 4 + r;
      if (rg2 < NN) out[rg2 * HD + col] = val;
      ls += val;
      lsq = fmaf(val, val, lsq);
    }
  }
#pragma unroll
  for (int off = 32; off > 0; off >>= 1) { ls += __shfl_down(ls, off); lsq += __shfl_down(lsq, off); }
  if ((tid & 63) == 0) { sred[(tid >> 6) * 2] = ls; sred[(tid >> 6) * 2 + 1] = lsq; }
  __syncthreads();
  if (tid == 0) {
    float S = 0.f, Q = 0.f;
#pragma unroll
    for (int i = 0; i < 8; ++i) { S += sred[i * 2]; Q += sred[i * 2 + 1]; }
    atomicAdd(&so[0], S);
    atomicAdd(&so[1], Q);
  }
}

// ---------------- classifier: out = bnrelu(h2) @ Wc^T + bc ----------------
__global__ __launch_bounds__(512) void k_cls(
    const float* __restrict__ h2, const float* __restrict__ Wc,
    const float* __restrict__ bc, const float* __restrict__ stats,
    const float* __restrict__ gp, const float* __restrict__ bp,
    float* __restrict__ out) {
  __shared__ char lds[45056];
  const int tid = threadIdx.x;
  const float m = stats[0] * (1.f / ((float)NN * (float)HD));
  const float var = stats[1] * (1.f / ((float)NN * (float)HD)) - m * m;
  const float inv = rsqrtf(var + EPSF);
  const float g = gp[0], bb = bp[0];
  const float a2 = g * inv, c2 = bb - g * m * inv;
  const int sr = tid >> 2, q = tid & 3;
  const size_t rg = (size_t)blockIdx.x * 128 + sr;
  {
    float4 gv[8];
#pragma unroll
    for (int i4 = 0; i4 < 8; ++i4) {
      const int c = q * 32 + i4 * 4;
      float4 t = (rg < NN) ? *(const float4*)(h2 + rg * HD + c) : make_float4(0.f, 0.f, 0.f, 0.f);
      t.x = fmaxf(fmaf(a2, t.x, c2), 0.f); t.y = fmaxf(fmaf(a2, t.y, c2), 0.f);
      t.z = fmaxf(fmaf(a2, t.z, c2), 0.f); t.w = fmaxf(fmaf(a2, t.w, c2), 0.f);
      gv[i4] = t;
    }
    cvt_write256(gv, lds + sr * 256, q, sr);
  }
  if (tid < 192) {
    const int bn = tid >> 2, bq = tid & 3;
    float4 gv[8];
#pragma unroll
    for (int i4 = 0; i4 < 8; ++i4) {
      const int c = bq * 32 + i4 * 4;
      gv[i4] = (bn < CD) ? *(const float4*)(Wc + (size_t)bn * HD + c) : make_float4(0.f, 0.f, 0.f, 0.f);
    }
    cvt_write256(gv, lds + 32768 + bn * 256, bq, bn);
  }
  __syncthreads();
  const int w = tid >> 6, l = tid & 63, lr = l & 15, lh = l >> 4;
  short8 af[4];
  const int arow = w * 16 + lr;
#pragma unroll
  for (int kk = 0; kk < 4; ++kk)
    af[kk] = *(short8*)(lds + arow * 256 + ((lh * 16 + kk * 64) ^ ((arow & 7) << 4)));
#pragma unroll
  for (int nt = 0; nt < 3; ++nt) {
    f32x4 acc = {0.f, 0.f, 0.f, 0.f};
#pragma unroll
    for (int kk = 0; kk < 4; ++kk) {
      const int n = nt * 16 + lr;
      short8 bfg = *(const short8*)(lds + 32768 + n * 256 + ((lh * 16 + kk * 64) ^ ((n & 7) << 4)));
      acc = __builtin_amdgcn_mfma_f32_16x16x32_bf16(af[kk], bfg, acc, 0, 0, 0);
    }
    const int col = nt * 16 + lr;
    if (col < CD) {
      const float bias = bc[col];
#pragma unroll
      for (int r = 0; r < 4; ++r) {
        const size_t rg2 = (size_t)blockIdx.x * 128 + w * 16 + lh * 4 + r;
        if (rg2 < NN) out[rg2 * CD + col] = acc[r] + bias;
      }
    }
  }
}

extern "C" void kernel_launch(void* const* d_in, const int* in_sizes, int n_in,
                              void* d_out, int out_size, void* d_ws, size_t ws_size,
                              hipStream_t stream) {
  const float* x   = (const float*)d_in[0];
  const float* nbr = (const float*)d_in[1];
  const int*   seg = (const int*)d_in[2];
  const float* W1x = (const float*)d_in[3];
  const float* W1n = (const float*)d_in[4];
  const float* g1  = (const float*)d_in[5];
  const float* b1  = (const float*)d_in[6];
  const float* W2x = (const float*)d_in[7];
  const float* W2n = (const float*)d_in[8];
  const float* g2  = (const float*)d_in[9];
  const float* b2  = (const float*)d_in[10];
  const float* Wc  = (const float*)d_in[11];
  const float* bc  = (const float*)d_in[12];
  float* out = (float*)d_out;

  char* p = (char*)d_ws;
  auto alloc = [&](size_t bytes) {
    char* q = p;
    p += (bytes + 255) & ~(size_t)255;
    return q;
  };
  int*    rp    = (int*)   alloc(sizeof(int) * (NN + 1));
  float*  fsum  = (float*) alloc(sizeof(float) * (size_t)NN * FD);
  float*  f2sum = (float*) alloc(sizeof(float) * (size_t)NN * HD);
  float*  hpre  = (float*) alloc(sizeof(float) * (size_t)NN * HD);
  float*  h2    = (float*) alloc(sizeof(float) * (size_t)NN * HD);
  float*  stats = (float*) alloc(sizeof(float) * 4);
  float*  es    = (float*) alloc(sizeof(float) * (size_t)NE);
  float*  eq    = (float*) alloc(sizeof(float) * (size_t)NE);
  float2* smi   = (float2*)alloc(sizeof(float2) * (size_t)NN);
  float*  rcv   = (float*) alloc(sizeof(float) * (size_t)NN);

  hipMemsetAsync(stats, 0, sizeof(float) * 4, stream);
  hipMemsetAsync(fsum, 0, sizeof(float) * (size_t)NN * FD, stream);
  hipMemsetAsync(f2sum, 0, sizeof(float) * (size_t)NN * HD, stream);

  k_rowptr<<<(NN + 256) / 256, 256, 0, stream>>>(seg, rp);
  k_gemm1<<<GRID_G1, 512, 0, stream>>>(nbr, seg, W1x, es, eq, fsum);
  k_nodestats<<<(NN + 255) / 256, 256, 0, stream>>>(rp, es, eq, smi, rcv);
  k_fuse2<<<GRID_G1, 512, 0, stream>>>(nbr, seg, W1x, smi, g1, b1, f2sum);
  k_ngemm<false><<<391, 512, 0, stream>>>(x, fsum, rcv, W1x, W1n, stats, g1, b1, hpre, stats);
  k_ngemm<true><<<391, 512, 0, stream>>>(hpre, f2sum, rcv, W2x, W2n, stats, g1, b1, h2, stats + 2);
  k_cls<<<391, 512, 0, stream>>>(h2, Wc, bc, stats + 2, g2, b2, out);
}